// Round 1
// 217.309 us; speedup vs baseline: 1.0302x; 1.0302x over previous
//
#include <hip/hip_runtime.h>
#include <math.h>

#define BATCH 8
#define CH    256
#define HWN   4096
#define DQK   16

typedef __attribute__((ext_vector_type(8))) short short8;
typedef __attribute__((ext_vector_type(4))) float float4v;

__device__ __forceinline__ unsigned short f2bf(float f) {
    union { float f; unsigned int u; } v; v.f = f;
    unsigned int r = v.u + 0x7FFF + ((v.u >> 16) & 1);   // RNE
    return (unsigned short)(r >> 16);
}
// HW packed f32->bf16 convert (RNE), T12 recipe: %1 -> low16, %2 -> high16
__device__ __forceinline__ unsigned int cvtpk(float lo, float hi) {
    unsigned int r;
    asm("v_cvt_pk_bf16_f32 %0, %1, %2" : "=v"(r) : "v"(lo), "v"(hi));
    return r;
}
// ft row permutation: stored row s holds key m with s4=m2, s3=m4, s2=m3
// (bits 0,1,5+ unchanged). Makes S^T output registers align with PV B-frag
// slots in the SAME lane (no cross-lane transpose needed).
__device__ __forceinline__ int perm_ft(int m) {
    return (m & ~28) | ((m & 24) >> 1) | ((m & 4) << 2);
}

// ---------------- kernel 0: W_cat -> bf16, biases -> bcat ----------------
__global__ __launch_bounds__(256) void wcast_kernel(
    const float* __restrict__ Wf, const float* __restrict__ bf_,
    const float* __restrict__ Wg, const float* __restrict__ bg,
    const float* __restrict__ Wh, const float* __restrict__ bh,
    unsigned short* __restrict__ Wbf, float* __restrict__ bcat)
{
    const int r = blockIdx.x;   // 288 rows
    const int t = threadIdx.x;  // 256 cols
    const float* src = (r < 16) ? (Wf + r*CH) : (r < 32) ? (Wg + (r-16)*CH) : (Wh + (r-32)*CH);
    Wbf[r*CH + t] = f2bf(src[t]);
    if (t == 0) bcat[r] = (r < 16) ? bf_[r] : (r < 32) ? bg[r-16] : bh[r-32];
}

// ---------------- kernel 1: x[b][c][px] fp32 -> xt[b][px][c] bf16 ----------------
__global__ __launch_bounds__(256) void xt_kernel(const float* __restrict__ x,
                                                 unsigned short* __restrict__ xt)
{
    const int t  = threadIdx.x;
    const int p0 = blockIdx.x * 64;
    const int c0 = blockIdx.y * 64;
    const int b  = blockIdx.z;
    __shared__ unsigned short tile[64][73];
    const int pc = t & 63;
    const int r0 = (t >> 6) * 16;
    #pragma unroll
    for (int j = 0; j < 16; j++) {
        int c = r0 + j;
        tile[pc][c] = f2bf(x[(size_t)(b*CH + c0 + c)*HWN + p0 + pc]);
    }
    __syncthreads();
    const int pr = t >> 2;
    const int cb = (t & 3) * 16;
    unsigned int outv[8];
    #pragma unroll
    for (int i = 0; i < 8; i++)
        outv[i] = (unsigned int)tile[pr][cb + 2*i] | ((unsigned int)tile[pr][cb + 2*i + 1] << 16);
    unsigned short* dst = &xt[(size_t)(b*HWN + p0 + pr)*CH + c0 + cb];
    *(uint4*)dst       = *(uint4*)&outv[0];
    *(uint4*)(dst + 8) = *(uint4*)&outv[4];
}

// ---------------- kernel 2: MFMA projection, rt-split x3 ----------------
// Grid (64 px-blocks, 8 b, 3 rt-groups of 6). C[288][4096] = Wbf @ bf16(x).
// A-frags direct from xt, B-frags direct from L2-hot Wbf. Group 0 holds
// ft (rt 0, perm_ft rows) and g (rt 1); h rows -> h3 fragment layout.
__global__ __launch_bounds__(256, 6) void proj_kernel(
    const unsigned short* __restrict__ xt, const unsigned short* __restrict__ Wbf,
    const float* __restrict__ bcat,
    unsigned short* __restrict__ ft, unsigned short* __restrict__ g,
    unsigned short* __restrict__ h3)
{
    const int t      = threadIdx.x;
    const int px0    = blockIdx.x * 64;
    const int b      = blockIdx.y;
    const int rtbase = blockIdx.z * 6;
    const int lane = t & 63, w = t >> 6, l15 = lane & 15, quad = lane >> 4;

    float4v acc[6];
    #pragma unroll
    for (int rt = 0; rt < 6; rt++) acc[rt] = (float4v){0.f,0.f,0.f,0.f};

    const unsigned short* xrow = &xt[((size_t)(b*HWN + px0 + w*16 + l15))*CH + quad*8];
    const unsigned short* wrow = &Wbf[(size_t)l15*CH + quad*8];

    #pragma unroll
    for (int ks = 0; ks < 8; ks++) {
        short8 afrag = *(const short8*)&xrow[ks*32];
        #pragma unroll
        for (int rt = 0; rt < 6; rt++) {
            short8 bfrag = *(const short8*)&wrow[(size_t)(rtbase + rt)*16*CH + ks*32];
            acc[rt] = __builtin_amdgcn_mfma_f32_16x16x32_bf16(afrag, bfrag, acc[rt], 0, 0, 0);
        }
    }

    const int pxl = px0 + w*16 + quad*4;      // this lane's px base (+r)
    const int mt  = (px0 >> 5) + (w >> 1);
    const int sub = ((w & 1)*2 + (quad >> 1))*128 + l15*8 + (quad & 1)*4;
    #pragma unroll
    for (int rt = 0; rt < 6; rt++) {
        const int R = rtbase + rt;            // uniform
        if (R == 0) {                         // -> ft at perm_ft rows
            float bv = bcat[l15];
            const int s0 = perm_ft(pxl);      // r only touches bits 0,1
            unsigned int p01 = cvtpk(acc[rt][0] + bv, acc[rt][1] + bv);
            unsigned int p23 = cvtpk(acc[rt][2] + bv, acc[rt][3] + bv);
            unsigned short* fp0 = &ft[((size_t)b*HWN + s0)*32];
            fp0[l15]       = (unsigned short)p01;         fp0[16 + l15]  = 0;
            fp0[32 + l15]  = (unsigned short)(p01 >> 16); fp0[48 + l15]  = 0;
            fp0[64 + l15]  = (unsigned short)p23;         fp0[80 + l15]  = 0;
            fp0[96 + l15]  = (unsigned short)(p23 >> 16); fp0[112 + l15] = 0;
        } else if (R == 1) {                  // -> g (4 consecutive px: uint2)
            float bv = bcat[16 + l15];
            unsigned int a01 = cvtpk(acc[rt][0] + bv, acc[rt][1] + bv);
            unsigned int a23 = cvtpk(acc[rt][2] + bv, acc[rt][3] + bv);
            *(uint2*)&g[(size_t)(b*DQK + l15)*HWN + pxl] = make_uint2(a01, a23);
        } else {                              // -> h3 frag layout
            float bv = bcat[R*16 + l15];
            unsigned int u0 = cvtpk(acc[rt][0] + bv, acc[rt][1] + bv);
            unsigned int u1 = cvtpk(acc[rt][2] + bv, acc[rt][3] + bv);
            *(uint2*)&h3[(((size_t)((b*128 + mt)*16 + (R-2))) << 9) + sub] = make_uint2(u0, u1);
        }
    }
}

// ---------------- kernel 3: MFMA flash attention, 8 waves ----------------
// Block = 512 thr, (batch, 64-q tile). Wave w = (qt=w>>1, half=w&1).
// SOFTWARE-PIPELINED: P (exp'd scores) for tile i are computed during tile
// i-1's PV phase, so the pre-barrier critical path is just one b128 pB
// write. Per iter: write pB -> barrier -> prefetch fr(i+2)/hr(i+1) ->
// S^T(i+1) 2 MFMA + 8 exp + 4 cvt_pk -> PV(i) 16 MFMA. Last iter peeled
// (write+PV only) so l is not double-counted.
__global__ __launch_bounds__(512, 4) void attn_kernel(
    const unsigned short* __restrict__ ft, const unsigned short* __restrict__ g,
    const unsigned short* __restrict__ h3, const float* __restrict__ x,
    const float* __restrict__ gamma_p, float* __restrict__ out)
{
    const int t    = threadIdx.x;
    const int b    = blockIdx.x & 7;          // batch -> XCD pin
    const int q0   = (blockIdx.x >> 3) * 64;
    const int lane = t & 63, w = t >> 6, l15 = lane & 15, quad = lane >> 4;
    const int qt_w = w >> 1, half = w & 1;

    __shared__ __align__(16) uint4 pB[2][2][4][64];   // [buf][grp][qt][lane] 16 KB
    __shared__ float l_l[4][16][2];

    union { short8 v; unsigned short u[8]; } gfrag;   // B[k=quad*8+j][q=l15] of q-tile qt_w
    #pragma unroll
    for (int j = 0; j < 8; j++) {
        int k = quad*8 + j;
        gfrag.u[j] = (k < DQK) ? g[(size_t)(b*DQK + k)*HWN + q0 + qt_w*16 + l15] : (unsigned short)0;
    }

    const unsigned short* ftb = ft + (size_t)b*HWN*32;
    const unsigned short* h3b = h3 + ((size_t)b << 20);

    short8 fr[2][2], hr[2][2][2];
    float4v acc[2][4];
    #pragma unroll
    for (int i = 0; i < 2; i++)
        #pragma unroll
        for (int j = 0; j < 4; j++) acc[i][j] = (float4v){0.f,0.f,0.f,0.f};
    float l_acc = 0.f;
    uint4 P;

    // ---- prologue: fr tile0 -> slot0, S^T(0)+exp -> P, fr tile1 -> slot1,
    //      hr tile0 -> slot0 ----
    #pragma unroll
    for (int j = 0; j < 2; j++)
        fr[0][j] = *(const short8*)&ftb[(size_t)((half*2 + j)*16 + l15)*32 + quad*8];
    {
        float4v z = {0.f,0.f,0.f,0.f};
        float4v s0v = __builtin_amdgcn_mfma_f32_16x16x32_bf16(fr[0][0], gfrag.v, z, 0, 0, 0);
        float4v s1v = __builtin_amdgcn_mfma_f32_16x16x32_bf16(fr[0][1], gfrag.v, z, 0, 0, 0);
        float e0 = __expf(s0v[0]), e1 = __expf(s0v[1]), e2 = __expf(s0v[2]), e3 = __expf(s0v[3]);
        float e4 = __expf(s1v[0]), e5 = __expf(s1v[1]), e6 = __expf(s1v[2]), e7 = __expf(s1v[3]);
        l_acc += (e0 + e1) + (e2 + e3) + (e4 + e5) + (e6 + e7);
        P = make_uint4(cvtpk(e0, e1), cvtpk(e2, e3), cvtpk(e4, e5), cvtpk(e6, e7));
    }
    #pragma unroll
    for (int j = 0; j < 2; j++)
        fr[1][j] = *(const short8*)&ftb[(size_t)(64 + (half*2 + j)*16 + l15)*32 + quad*8];
    #pragma unroll
    for (int grp = 0; grp < 2; grp++)
        #pragma unroll
        for (int ctl = 0; ctl < 2; ctl++)
            hr[0][grp][ctl] = *(const short8*)&h3b[(((size_t)(grp*16 + w*2 + ctl)) << 9) + lane*8];

    // Per-iter slots: S^T(i+1) reads fr[(i+1)&1]; prefetch fr tile i+2 ->
    // slot i&1 (consumed at iter i-1). PV(i) reads hr[i&1]; prefetch hr tile
    // i+1 -> slot (i+1)&1 (consumed at iter i-1's PV). pB[i&1] written after
    // barrier(i-1); its last readers (iter i-2) consumed it pre-barrier(i-1).
#define ATTN_STEP(u, i, DO_NEXT) do {                                          \
    pB[u][half][qt_w][lane] = P;                                               \
    __syncthreads();                                                           \
    if (DO_NEXT) {                                                             \
      const int nf = ((i) + 2) & 63;                                           \
      _Pragma("unroll")                                                        \
      for (int j = 0; j < 2; j++)                                              \
        fr[u][j] = *(const short8*)&ftb[(size_t)(nf*64 + (half*2 + j)*16 + l15)*32 + quad*8]; \
      const int nh = ((i) + 1) & 63;                                           \
      _Pragma("unroll")                                                        \
      for (int grp = 0; grp < 2; grp++)                                        \
        _Pragma("unroll")                                                      \
        for (int ctl = 0; ctl < 2; ctl++)                                      \
          hr[(u)^1][grp][ctl] = *(const short8*)&h3b[(((size_t)((nh*2 + grp)*16 + w*2 + ctl)) << 9) + lane*8]; \
      float4v z = {0.f,0.f,0.f,0.f};                                           \
      float4v s0v = __builtin_amdgcn_mfma_f32_16x16x32_bf16(fr[(u)^1][0], gfrag.v, z, 0, 0, 0); \
      float4v s1v = __builtin_amdgcn_mfma_f32_16x16x32_bf16(fr[(u)^1][1], gfrag.v, z, 0, 0, 0); \
      float e0 = __expf(s0v[0]), e1 = __expf(s0v[1]), e2 = __expf(s0v[2]), e3 = __expf(s0v[3]); \
      float e4 = __expf(s1v[0]), e5 = __expf(s1v[1]), e6 = __expf(s1v[2]), e7 = __expf(s1v[3]); \
      l_acc += (e0 + e1) + (e2 + e3) + (e4 + e5) + (e6 + e7);                  \
      P = make_uint4(cvtpk(e0, e1), cvtpk(e2, e3), cvtpk(e4, e5), cvtpk(e6, e7)); \
    }                                                                          \
    _Pragma("unroll")                                                          \
    for (int grp = 0; grp < 2; grp++) {                                        \
      _Pragma("unroll")                                                        \
      for (int qt = 0; qt < 4; qt++) {                                         \
        union { uint4 uu; short8 v; } bq;                                      \
        bq.uu = pB[u][grp][qt][lane];                                          \
        _Pragma("unroll")                                                      \
        for (int ctl = 0; ctl < 2; ctl++)                                      \
          acc[ctl][qt] = __builtin_amdgcn_mfma_f32_16x16x32_bf16(hr[u][grp][ctl], bq.v, acc[ctl][qt], 0, 0, 0); \
      }                                                                        \
    }                                                                          \
  } while (0)

    for (int i0 = 0; i0 < 62; i0 += 2) {
        ATTN_STEP(0, i0, 1);
        ATTN_STEP(1, i0 + 1, 1);
    }
    ATTN_STEP(0, 62, 1);   // computes S^T(63)+P; fr prefetch wraps (dead)
    ATTN_STEP(1, 63, 0);   // peeled tail: write P(63), PV(63) only
#undef ATTN_STEP

    // ---- l: reduce over quads; combine halves via LDS ----
    l_acc += __shfl_xor(l_acc, 16, 64);
    l_acc += __shfl_xor(l_acc, 32, 64);
    if (quad == 0) l_l[qt_w][l15][half] = l_acc;
    __syncthreads();

    const float gamma = *gamma_p;
    float linv[4];
    #pragma unroll
    for (int qt = 0; qt < 4; qt++) linv[qt] = 1.f / (l_l[qt][l15][0] + l_l[qt][l15][1]);
    #pragma unroll
    for (int ctl = 0; ctl < 2; ctl++) {
        #pragma unroll
        for (int r = 0; r < 4; r++) {
            int c = w*32 + ctl*16 + quad*4 + r;
            size_t base = (size_t)(b*CH + c)*HWN + q0;
            #pragma unroll
            for (int qt = 0; qt < 4; qt++) {
                size_t o = base + qt*16 + l15;
                out[o] = gamma * acc[ctl][qt][r] * linv[qt] + x[o];
            }
        }
    }
}

extern "C" void kernel_launch(void* const* d_in, const int* in_sizes, int n_in,
                              void* d_out, int out_size, void* d_ws, size_t ws_size,
                              hipStream_t stream) {
    const float* x     = (const float*)d_in[0];
    const float* Wf    = (const float*)d_in[1];
    const float* bf_   = (const float*)d_in[2];
    const float* Wg    = (const float*)d_in[3];
    const float* bg    = (const float*)d_in[4];
    const float* Wh    = (const float*)d_in[5];
    const float* bh    = (const float*)d_in[6];
    const float* gamma = (const float*)d_in[7];
    float* out = (float*)d_out;

    // ws: xt 16.8MB | ft 2MB | g 1MB | h3 16.8MB | Wbf 147KB | bcat
    unsigned short* xt   = (unsigned short*)d_ws;
    unsigned short* ftp  = xt  + (size_t)BATCH*HWN*CH;
    unsigned short* g    = ftp + (size_t)BATCH*HWN*32;
    unsigned short* h3   = g   + (size_t)BATCH*DQK*HWN;
    unsigned short* Wbf  = h3  + (size_t)BATCH*128*16*512;
    float*          bcat = (float*)(Wbf + 288*CH);

    wcast_kernel<<<dim3(288), 256, 0, stream>>>(Wf, bf_, Wg, bg, Wh, bh, Wbf, bcat);
    xt_kernel<<<dim3(HWN/64, CH/64, BATCH), 256, 0, stream>>>(x, xt);
    proj_kernel<<<dim3(HWN/64, BATCH, 3), 256, 0, stream>>>(xt, Wbf, bcat, ftp, g, h3);
    attn_kernel<<<dim3((HWN/64)*BATCH), 512, 0, stream>>>(ftp, g, h3, x, gamma, out);
}